// Round 8
// baseline (157.845 us; speedup 1.0000x reference)
//
#include <hip/hip_runtime.h>

// ---------- helpers ----------
static __device__ __forceinline__ float bf2f(unsigned short u) {
    return __uint_as_float(((unsigned int)u) << 16);
}
static __device__ __forceinline__ unsigned short f2bf(float f) {
    unsigned int x = __float_as_uint(f);
    unsigned int lsb = (x >> 16) & 1u;
    x += 0x7fffu + lsb;                 // round-to-nearest-even
    return (unsigned short)(x >> 16);
}

typedef __attribute__((ext_vector_type(8))) short short8;    // 8 bf16 = 4 VGPRs (MFMA A/B frag)
typedef __attribute__((ext_vector_type(4))) float floatx4;   // MFMA C/D frag

static __device__ __forceinline__ short8 ldg8(const unsigned short* p) {
    short8 v; __builtin_memcpy(&v, p, 16); return v;
}

// ---------- repack + convert (fused): weights -> bf16 transposed packs, activations -> bf16 ----------
// Wpack_t[inp][n][k] (n=proj*256+h*32+e); inp0=[e2p_Wq|p2e_Wk|p2e_Wv], inp1=[p2e_Wq|e2p_Wk|e2p_Wv]
// Wopack_t[dir][n][k] = Wo[k][n] ; bias_pack[inp][768] fp32 ; bias2[dir][256] fp32 ; Abf = bf16(eeg|pps)
__global__ __launch_bounds__(256) void repack_kernel(
    const float* e2p_Wq, const float* e2p_bq,
    const float* e2p_Wk, const float* e2p_bk,
    const float* e2p_Wv, const float* e2p_bv,
    const float* e2p_Wo, const float* e2p_bo,
    const float* p2e_Wq, const float* p2e_bq,
    const float* p2e_Wk, const float* p2e_bk,
    const float* p2e_Wv, const float* p2e_bv,
    const float* p2e_Wo, const float* p2e_bo,
    const float* eeg, const float* pps,
    unsigned short* Wpack, unsigned short* Wopack, float* bias_pack, float* bias2,
    unsigned short* Abf)
{
    int idx = blockIdx.x * 256 + threadIdx.x;
    const int WP = 2 * 768 * 256;
    if (idx < WP) {
        int inp = idx / (768 * 256);
        int rem = idx % (768 * 256);
        int n = rem / 256, k = rem % 256;
        int proj = n / 256, h = (n % 256) / 32, e = n % 32;
        const float* W;
        if (inp == 0) W = (proj == 0) ? e2p_Wq : (proj == 1) ? p2e_Wk : p2e_Wv;
        else          W = (proj == 0) ? p2e_Wq : (proj == 1) ? e2p_Wk : e2p_Wv;
        Wpack[idx] = f2bf(W[h * 8192 + k * 32 + e]);   // W[h][d=k][e], strides (8192,32,1)
    }
    int idx2 = idx - WP;
    if (idx2 >= 0 && idx2 < 2 * 65536) {
        int dir = idx2 / 65536, rem2 = idx2 % 65536;
        int n = rem2 / 256, k = rem2 % 256;
        Wopack[idx2] = f2bf((dir == 0 ? e2p_Wo : p2e_Wo)[k * 256 + n]);   // transposed
    }
    if (idx < 1536) {
        int inp = idx / 768, n = idx % 768;
        int proj = n / 256, he = n % 256;
        const float* bsrc;
        if (inp == 0) bsrc = (proj == 0) ? e2p_bq : (proj == 1) ? p2e_bk : p2e_bv;
        else          bsrc = (proj == 0) ? p2e_bq : (proj == 1) ? e2p_bk : e2p_bv;
        bias_pack[idx] = bsrc[he];
    }
    if (idx >= 1536 && idx < 2048) {
        int j = idx - 1536;
        int dir = j / 256, n = j % 256;
        bias2[j] = (dir == 0 ? e2p_bo : p2e_bo)[n];
    }
    // convert: 524288 threads x 8 floats = eeg(2.1M) + pps(2.1M)
    {
        long base = (long)idx * 8;
        const float* src = (base < 2097152) ? eeg : pps;
        long off = (base < 2097152) ? base : base - 2097152;
        float v[8];
        __builtin_memcpy(v, src + off, 32);
        unsigned short o[8];
        #pragma unroll
        for (int j = 0; j < 8; ++j) o[j] = f2bf(v[j]);
        __builtin_memcpy(Abf + base, o, 16);
    }
}

// ---------- MFMA GEMM, barrier-free K-loop (unchanged from round 7; QKV only now) ----------
template<bool C_F32>
__global__ __launch_bounds__(256) void mfma_gemm_kernel(
    const unsigned short* __restrict__ A0, const unsigned short* __restrict__ A1,
    const unsigned short* __restrict__ B0t, const unsigned short* __restrict__ B1t,
    const float* __restrict__ bias0, const float* __restrict__ bias1,
    void* __restrict__ C0v, void* __restrict__ C1v,
    int N)
{
    __shared__ __align__(16) unsigned short Cs[128][136];   // epilogue only

    const int z = blockIdx.z;
    const unsigned short* A = z ? A1 : A0;
    const unsigned short* Bt = z ? B1t : B0t;
    const float* bias = z ? bias1 : bias0;
    void* Cv = z ? C1v : C0v;

    const int tid = threadIdx.x;
    const long m0 = (long)blockIdx.x * 128;
    const int n0 = blockIdx.y * 128;

    const int lane = tid & 63;
    const int wv = tid >> 6;
    const int wm = (wv >> 1) * 64, wn = (wv & 1) * 64;
    const int fr = lane & 15;
    const int fq = (lane >> 4) * 8;

    const unsigned short* Ap = A + (m0 + wm + fr) * 256 + fq;
    const unsigned short* Bp = Bt + (long)(n0 + wn + fr) * 256 + fq;

    floatx4 acc[4][4] = {};
    short8 af[2][4], bf_[2][4];

    #pragma unroll
    for (int i = 0; i < 4; ++i) af[0][i] = ldg8(Ap + i * 4096);
    #pragma unroll
    for (int j = 0; j < 4; ++j) bf_[0][j] = ldg8(Bp + j * 4096);

    #pragma unroll
    for (int kc = 0; kc < 8; ++kc) {
        const int cur = kc & 1, nxt = cur ^ 1;
        if (kc < 7) {
            const int ko = (kc + 1) * 32;
            #pragma unroll
            for (int i = 0; i < 4; ++i) af[nxt][i] = ldg8(Ap + ko + i * 4096);
            #pragma unroll
            for (int j = 0; j < 4; ++j) bf_[nxt][j] = ldg8(Bp + ko + j * 4096);
        }
        #pragma unroll
        for (int i = 0; i < 4; ++i)
            #pragma unroll
            for (int j = 0; j < 4; ++j)
                acc[i][j] = __builtin_amdgcn_mfma_f32_16x16x32_bf16(af[cur][i], bf_[cur][j], acc[i][j], 0, 0, 0);
    }

    float bj[4];
    #pragma unroll
    for (int j = 0; j < 4; ++j) bj[j] = bias[n0 + wn + j * 16 + fr];

    const int cr0 = wm + ((lane >> 4) << 2);
    #pragma unroll
    for (int i = 0; i < 4; ++i)
        #pragma unroll
        for (int j = 0; j < 4; ++j)
            #pragma unroll
            for (int r = 0; r < 4; ++r)
                Cs[cr0 + i * 16 + r][wn + j * 16 + fr] = f2bf(acc[i][j][r] + bj[j]);
    __syncthreads();

    const int rr = tid >> 4, cc = (tid & 15) * 8;
    #pragma unroll
    for (int p = 0; p < 8; ++p) {
        int r = p * 16 + rr;
        unsigned short tmp[8];
        __builtin_memcpy(tmp, &Cs[r][cc], 16);
        if (C_F32) {
            float of[8];
            #pragma unroll
            for (int j = 0; j < 8; ++j) of[j] = bf2f(tmp[j]);
            __builtin_memcpy((float*)Cv + (m0 + r) * N + n0 + cc, of, 32);
        } else {
            __builtin_memcpy((unsigned short*)Cv + (m0 + r) * N + n0 + cc, tmp, 16);
        }
    }
}

// ---------- fused MFMA attention + output projection ----------
// Block = (s-tile of 16, b, dir), 512 thr = 8 waves, one head per wave.
// K rows 0..47 / V rows 0..63 (kv_s = s0-15+r) staged in LDS; OOB rows = bias vectors
// (NOT masked - reference pads kv BEFORE projection); rows beyond the band are masked anyway.
// Scores (3 MFMAs) -> band mask -> softmax -> P (aliased over K) -> PV (4 MFMAs, P cols
// 48..63 zeroed) -> att tile 16x256 in LDS -> outproj (16 MFMAs/wave, Wo_t direct global)
// -> +bias2 -> fp32 out. No att intermediate in HBM.
#define KROWS 48
#define VROWS 64
#define KVSTR 264
__global__ __launch_bounds__(512) void attn_out_kernel(
    const unsigned short* __restrict__ Y, const float* __restrict__ bias_pack,
    const unsigned short* __restrict__ Wopack, const float* __restrict__ bias2,
    float* __restrict__ out)
{
    __shared__ unsigned short smem[(KROWS + VROWS) * KVSTR];   // 59136 B
    unsigned short* Ks = smem;                      // 48 x 264
    unsigned short* Vs = smem + KROWS * KVSTR;      // 64 x 264
    unsigned short (*Ps)[16][72] = (unsigned short(*)[16][72])smem;   // aliased over K (after scores)
    unsigned short (*As)[KVSTR] = (unsigned short(*)[KVSTR])smem;     // att tile (after PV)

    const int s0 = blockIdx.x * 16;
    const int b = blockIdx.y, dir = blockIdx.z;
    const int kvinp = 1 - dir;
    const int tid = threadIdx.x;

    const float* bkv = bias_pack + kvinp * 768;
    const long kvbase = ((long)kvinp * 8192 + b * 2048) * 768;

    // ---- stage V (64 rows) and K (48 rows), 32 e per task ----
    {
        const int r = tid >> 3, seg = (tid & 7) * 32;
        int p = s0 - 15 + r;
        unsigned short vr[32];
        if (p >= 0 && p < 2048) {
            __builtin_memcpy(vr, Y + kvbase + (long)p * 768 + 512 + seg, 64);
        } else {
            #pragma unroll
            for (int j = 0; j < 32; ++j) vr[j] = f2bf(bkv[512 + seg + j]);
        }
        __builtin_memcpy(&Vs[r * KVSTR + seg], vr, 64);
        if (tid < 384) {   // K rows 0..47
            unsigned short kr[32];
            if (p >= 0 && p < 2048) {
                __builtin_memcpy(kr, Y + kvbase + (long)p * 768 + 256 + seg, 64);
            } else {
                #pragma unroll
                for (int j = 0; j < 32; ++j) kr[j] = f2bf(bkv[256 + seg + j]);
            }
            __builtin_memcpy(&Ks[r * KVSTR + seg], kr, 64);
        }
    }

    // ---- Q fragment (A-layout) direct from global ----
    const int lane = tid & 63;
    const int wv = tid >> 6;                    // head index 0..7
    const int fr = lane & 15, q4 = lane >> 4;
    short8 aq = ldg8(Y + ((long)dir * 8192 + b * 2048 + s0 + fr) * 768 + wv * 32 + q4 * 8);

    __syncthreads();   // (1) staging complete

    // ---- scores: S[16 s][48 kv] via 3 MFMAs ----
    floatx4 sacc[3] = {};
    #pragma unroll
    for (int kvt = 0; kvt < 3; ++kvt) {
        short8 bk_ = *(const short8*)&Ks[(kvt * 16 + fr) * KVSTR + wv * 32 + q4 * 8];
        sacc[kvt] = __builtin_amdgcn_mfma_f32_16x16x32_bf16(aq, bk_, sacc[kvt], 0, 0, 0);
    }

    // ---- band mask + softmax (row i = q4*4+reg; kv col jc; 0 <= jc - i <= 30) ----
    float sv[3][4];
    float mx[4] = {-3.0e38f, -3.0e38f, -3.0e38f, -3.0e38f};
    #pragma unroll
    for (int kvt = 0; kvt < 3; ++kvt)
        #pragma unroll
        for (int reg = 0; reg < 4; ++reg) {
            int i = q4 * 4 + reg;
            int jc = kvt * 16 + fr;
            int d = jc - i;
            float x = (d >= 0 && d <= 30) ? sacc[kvt][reg] * 0.17677669529663687f : -3.0e38f;
            sv[kvt][reg] = x;
            mx[reg] = fmaxf(mx[reg], x);
        }
    #pragma unroll
    for (int off = 1; off < 16; off <<= 1)
        #pragma unroll
        for (int reg = 0; reg < 4; ++reg)
            mx[reg] = fmaxf(mx[reg], __shfl_xor(mx[reg], off));
    float ps[4] = {};
    #pragma unroll
    for (int kvt = 0; kvt < 3; ++kvt)
        #pragma unroll
        for (int reg = 0; reg < 4; ++reg) {
            float e = __expf(sv[kvt][reg] - mx[reg]);
            sv[kvt][reg] = e;
            ps[reg] += e;
        }
    #pragma unroll
    for (int off = 1; off < 16; off <<= 1)
        #pragma unroll
        for (int reg = 0; reg < 4; ++reg)
            ps[reg] += __shfl_xor(ps[reg], off);

    __syncthreads();   // (2) all scores read from K; P may now overwrite K region

    // ---- P -> LDS bf16 (cols 48..63 zeroed for the K=64 PV) ----
    #pragma unroll
    for (int reg = 0; reg < 4; ++reg) {
        int i = q4 * 4 + reg;
        #pragma unroll
        for (int kvt = 0; kvt < 3; ++kvt)
            Ps[wv][i][kvt * 16 + fr] = f2bf(sv[kvt][reg]);
        Ps[wv][i][48 + fr] = 0;
    }
    // same-wave LDS RAW (P write -> P read) is ordered by lgkmcnt; no barrier needed.

    // ---- PV: O[16 s][32 e] via 4 MFMAs (A = own P, B = V^T strided) ----
    floatx4 oacc[2] = {};
    #pragma unroll
    for (int ch = 0; ch < 2; ++ch) {
        short8 ap = *(const short8*)&Ps[wv][fr][ch * 32 + q4 * 8];
        #pragma unroll
        for (int et = 0; et < 2; ++et) {
            short8 bv;
            #pragma unroll
            for (int j = 0; j < 8; ++j)
                bv[j] = (short)Vs[(ch * 32 + q4 * 8 + j) * KVSTR + wv * 32 + et * 16 + fr];
            oacc[et] = __builtin_amdgcn_mfma_f32_16x16x32_bf16(ap, bv, oacc[et], 0, 0, 0);
        }
    }

    float rs[4];
    #pragma unroll
    for (int reg = 0; reg < 4; ++reg) rs[reg] = 1.0f / ps[reg];

    __syncthreads();   // (3) all PV reads of P/V done; att tile may overwrite

    #pragma unroll
    for (int et = 0; et < 2; ++et)
        #pragma unroll
        for (int reg = 0; reg < 4; ++reg)
            As[q4 * 4 + reg][wv * 32 + et * 16 + fr] = f2bf(oacc[et][reg] * rs[reg]);

    __syncthreads();   // (4) att tile complete

    // ---- output projection: out[16 x 256] = att @ Wo_t^T + bias2 (per wave: 32 n-cols) ----
    const unsigned short* Wo = Wopack + dir * 65536;
    const int nw = wv * 32;
    floatx4 oa[2] = {};
    #pragma unroll
    for (int kc = 0; kc < 8; ++kc) {
        short8 ap = *(const short8*)&As[fr][kc * 32 + q4 * 8];
        #pragma unroll
        for (int j = 0; j < 2; ++j) {
            short8 bw = ldg8(Wo + (nw + j * 16 + fr) * 256 + kc * 32 + q4 * 8);
            oa[j] = __builtin_amdgcn_mfma_f32_16x16x32_bf16(ap, bw, oa[j], 0, 0, 0);
        }
    }

    float bj[2];
    #pragma unroll
    for (int j = 0; j < 2; ++j) bj[j] = bias2[dir * 256 + nw + j * 16 + fr];

    float* outp = out + (long)dir * 2097152;
    #pragma unroll
    for (int j = 0; j < 2; ++j)
        #pragma unroll
        for (int reg = 0; reg < 4; ++reg) {
            int i = q4 * 4 + reg;
            outp[((long)b * 2048 + s0 + i) * 256 + nw + j * 16 + fr] = oa[j][reg] + bj[j];
        }
}

// ---------- launch ----------
extern "C" void kernel_launch(void* const* d_in, const int* in_sizes, int n_in,
                              void* d_out, int out_size, void* d_ws, size_t ws_size,
                              hipStream_t stream)
{
    float* out = (float*)d_out;

    char* ws = (char*)d_ws;
    unsigned short* Wpack   = (unsigned short*)(ws + 0);          // 786432 B (transposed)
    unsigned short* Wopack  = (unsigned short*)(ws + 786432);     // 262144 B (transposed)
    float*          biasP   = (float*)(ws + 1048576);             // 6144 B
    float*          bias2   = (float*)(ws + 1054720);             // 2048 B
    unsigned short* Y       = (unsigned short*)(ws + 1056768);    // 25165824 B
    unsigned short* Abf     = (unsigned short*)(ws + 26222592);   // 8388608 B (bf16 activations)

    repack_kernel<<<2048, 256, 0, stream>>>(
        (const float*)d_in[2],  (const float*)d_in[3],
        (const float*)d_in[4],  (const float*)d_in[5],
        (const float*)d_in[6],  (const float*)d_in[7],
        (const float*)d_in[8],  (const float*)d_in[9],
        (const float*)d_in[10], (const float*)d_in[11],
        (const float*)d_in[12], (const float*)d_in[13],
        (const float*)d_in[14], (const float*)d_in[15],
        (const float*)d_in[16], (const float*)d_in[17],
        (const float*)d_in[0],  (const float*)d_in[1],
        Wpack, Wopack, biasP, bias2, Abf);

    // fused QKV projection: Abf(8192x256) @ Wpack_t^T (768x256) + bias -> Y (bf16)
    mfma_gemm_kernel<false><<<dim3(64, 6, 2), 256, 0, stream>>>(
        Abf, Abf + 2097152, Wpack, Wpack + 196608, biasP, biasP + 768,
        Y, Y + 8192 * 768, 768);

    // fused windowed attention + output projection -> d_out (fp32)
    attn_out_kernel<<<dim3(128, 4, 2), 512, 0, stream>>>(Y, biasP, Wopack, bias2, out);
}

// Round 9
// 140.377 us; speedup vs baseline: 1.1244x; 1.1244x over previous
//
#include <hip/hip_runtime.h>

// ---------- helpers ----------
static __device__ __forceinline__ float bf2f(unsigned short u) {
    return __uint_as_float(((unsigned int)u) << 16);
}
static __device__ __forceinline__ unsigned short f2bf(float f) {
    unsigned int x = __float_as_uint(f);
    unsigned int lsb = (x >> 16) & 1u;
    x += 0x7fffu + lsb;                 // round-to-nearest-even
    return (unsigned short)(x >> 16);
}

typedef __attribute__((ext_vector_type(8))) short short8;    // 8 bf16 = 4 VGPRs (MFMA A/B frag)
typedef __attribute__((ext_vector_type(4))) float floatx4;   // MFMA C/D frag

static __device__ __forceinline__ short8 ldg8(const unsigned short* p) {
    short8 v; __builtin_memcpy(&v, p, 16); return v;
}

// ======================================================================
// FRAGMENT-MAJOR LAYOUT for MFMA operands (16x16x32 bf16):
//   element (row r, k) -> group g=r>>4, fr=r&15, kc=k>>5, q4=(k>>3)&3, j=k&7
//   offset = (g*8 + kc)*512 + (q4*16 + fr)*8 + j      [512 shorts per frag-slot]
// A wave's fragment load = base + lane*8 (lane=q4*16+fr) -> 64 lanes x 16B
// contiguous = ONE coalesced 1KB transaction (vs 64 scattered lines row-major).
// Abf: per input 8192x256 -> 4096 slots. Wpack: per input 768x256 -> 384 slots.
// Wopack: per dir 256x256 -> 128 slots.
// ======================================================================

// ---------- repack + convert: weights & activations -> bf16 frag-major; biases fp32 ----------
__global__ __launch_bounds__(256) void repack_kernel(
    const float* e2p_Wq, const float* e2p_bq,
    const float* e2p_Wk, const float* e2p_bk,
    const float* e2p_Wv, const float* e2p_bv,
    const float* e2p_Wo, const float* e2p_bo,
    const float* p2e_Wq, const float* p2e_bq,
    const float* p2e_Wk, const float* p2e_bk,
    const float* p2e_Wv, const float* p2e_bv,
    const float* p2e_Wo, const float* p2e_bo,
    const float* eeg, const float* pps,
    unsigned short* Wpack, unsigned short* Wopack, float* bias_pack, float* bias2,
    unsigned short* Abf)
{
    const int idx = blockIdx.x * 256 + threadIdx.x;

    // --- QKV weights: 2 inputs x 768 n x 32 k-slots = 49152 slots of 8 ---
    if (idx < 49152) {
        int inp = idx / 24576, r = idx % 24576;
        int n = r >> 5, k8 = r & 31;
        int kc = k8 >> 2, q4 = k8 & 3, kb = k8 * 8;
        int proj = n / 256, h = (n % 256) / 32, e = n % 32;
        const float* W;
        if (inp == 0) W = (proj == 0) ? e2p_Wq : (proj == 1) ? p2e_Wk : p2e_Wv;
        else          W = (proj == 0) ? p2e_Wq : (proj == 1) ? e2p_Wk : e2p_Wv;
        unsigned short o[8];
        #pragma unroll
        for (int j = 0; j < 8; ++j) o[j] = f2bf(W[h * 8192 + (kb + j) * 32 + e]);
        __builtin_memcpy(Wpack + inp * 196608 + ((n >> 4) * 8 + kc) * 512 + (q4 * 16 + (n & 15)) * 8, o, 16);
    }
    // --- Wo: 2 dirs x 256 n x 32 k-slots = 16384 slots (row n of Wo^T = col n of Wo) ---
    int i2 = idx - 49152;
    if (i2 >= 0 && i2 < 16384) {
        int dir = i2 / 8192, r = i2 % 8192;
        int n = r >> 5, k8 = r & 31;
        int kc = k8 >> 2, q4 = k8 & 3, kb = k8 * 8;
        const float* Wo = dir ? p2e_Wo : e2p_Wo;
        unsigned short o[8];
        #pragma unroll
        for (int j = 0; j < 8; ++j) o[j] = f2bf(Wo[(kb + j) * 256 + n]);
        __builtin_memcpy(Wopack + dir * 65536 + ((n >> 4) * 8 + kc) * 512 + (q4 * 16 + (n & 15)) * 8, o, 16);
    }
    // --- biases (fp32, row-major) ---
    if (idx < 1536) {
        int inp = idx / 768, n = idx % 768;
        int proj = n / 256, he = n % 256;
        const float* bsrc;
        if (inp == 0) bsrc = (proj == 0) ? e2p_bq : (proj == 1) ? p2e_bk : p2e_bv;
        else          bsrc = (proj == 0) ? p2e_bq : (proj == 1) ? e2p_bk : e2p_bv;
        bias_pack[idx] = bsrc[he];
    }
    if (idx >= 1536 && idx < 2048) {
        int j = idx - 1536;
        int dir = j / 256, n = j % 256;
        bias2[j] = (dir == 0 ? e2p_bo : p2e_bo)[n];
    }
    // --- convert activations -> frag-major bf16: 524288 threads x 8 elems ---
    {
        int m_total = idx >> 5;                 // 0..16383
        int k8 = idx & 31;
        int inp = m_total >> 13, m = m_total & 8191;
        int kc = k8 >> 2, q4 = k8 & 3, kb = k8 * 8;
        const float* src = inp ? pps : eeg;
        float v[8];
        __builtin_memcpy(v, src + (long)m * 256 + kb, 32);   // coalesced 32B read
        unsigned short o[8];
        #pragma unroll
        for (int j = 0; j < 8; ++j) o[j] = f2bf(v[j]);
        __builtin_memcpy(Abf + inp * 2097152 + (((m >> 4) * 8 + kc) * 512 + (q4 * 16 + (m & 15)) * 8), o, 16);
    }
}

// ---------- MFMA GEMM, barrier-free K-loop, frag-major operands ----------
// C[8192 x N] = A @ B^T + bias; A,B in frag-major layout. 128x128 tile, 4 waves
// (2x2 quadrants of 64x64, 4x4 MFMAs each). All loads 1KB-coalesced; LDS only
// for the coalescing epilogue. grid (m_tiles, n_tiles, input).
__global__ __launch_bounds__(256) void mfma_gemm_kernel(
    const unsigned short* __restrict__ A0, const unsigned short* __restrict__ A1,
    const unsigned short* __restrict__ B0f, const unsigned short* __restrict__ B1f,
    const float* __restrict__ bias0, const float* __restrict__ bias1,
    unsigned short* __restrict__ C0, unsigned short* __restrict__ C1,
    int N)
{
    __shared__ __align__(16) unsigned short Cs[128][136];   // epilogue only

    const int z = blockIdx.z;
    const unsigned short* A = z ? A1 : A0;
    const unsigned short* Bf = z ? B1f : B0f;
    const float* bias = z ? bias1 : bias0;
    unsigned short* C = z ? C1 : C0;

    const int tid = threadIdx.x;
    const long m0 = (long)blockIdx.x * 128;
    const int n0 = blockIdx.y * 128;

    const int lane = tid & 63;
    const int wv = tid >> 6;
    const int wm = (wv >> 1) * 64, wn = (wv & 1) * 64;
    const int fr = lane & 15, q4 = lane >> 4;

    // frag-major bases: A-frag i at +(i*8+kc)*512, B-frag j at +(j*8+kc)*512
    const unsigned short* Aw = A + ((blockIdx.x * 8 + (wm >> 4)) * 8) * 512 + lane * 8;
    const unsigned short* Bw = Bf + ((blockIdx.y * 8 + (wn >> 4)) * 8) * 512 + lane * 8;

    floatx4 acc[4][4] = {};
    short8 af[2][4], bf_[2][4];

    #pragma unroll
    for (int i = 0; i < 4; ++i) af[0][i] = ldg8(Aw + i * 4096);
    #pragma unroll
    for (int j = 0; j < 4; ++j) bf_[0][j] = ldg8(Bw + j * 4096);

    #pragma unroll
    for (int kc = 0; kc < 8; ++kc) {
        const int cur = kc & 1, nxt = cur ^ 1;
        if (kc < 7) {
            #pragma unroll
            for (int i = 0; i < 4; ++i) af[nxt][i] = ldg8(Aw + (i * 8 + kc + 1) * 512);
            #pragma unroll
            for (int j = 0; j < 4; ++j) bf_[nxt][j] = ldg8(Bw + (j * 8 + kc + 1) * 512);
        }
        #pragma unroll
        for (int i = 0; i < 4; ++i)
            #pragma unroll
            for (int j = 0; j < 4; ++j)
                acc[i][j] = __builtin_amdgcn_mfma_f32_16x16x32_bf16(af[cur][i], bf_[cur][j], acc[i][j], 0, 0, 0);
    }

    float bj[4];
    #pragma unroll
    for (int j = 0; j < 4; ++j) bj[j] = bias[n0 + wn + j * 16 + fr];

    const int cr0 = wm + (q4 << 2);
    #pragma unroll
    for (int i = 0; i < 4; ++i)
        #pragma unroll
        for (int j = 0; j < 4; ++j)
            #pragma unroll
            for (int r = 0; r < 4; ++r)
                Cs[cr0 + i * 16 + r][wn + j * 16 + fr] = f2bf(acc[i][j][r] + bj[j]);
    __syncthreads();

    const int rr = tid >> 4, cc = (tid & 15) * 8;
    #pragma unroll
    for (int p = 0; p < 8; ++p) {
        int r = p * 16 + rr;
        unsigned short tmp[8];
        __builtin_memcpy(tmp, &Cs[r][cc], 16);
        __builtin_memcpy(C + (m0 + r) * N + n0 + cc, tmp, 16);
    }
}

// ---------- fused MFMA attention + output projection ----------
// Block = (s-tile of 16, b, dir), 512 thr = 8 waves, one head per wave.
// K rows 0..47 / V rows 0..63 staged in LDS (OOB rows = bias vectors, NOT masked —
// reference pads kv BEFORE projection). Scores (3 MFMAs) -> band mask -> softmax ->
// P (aliased over K) -> PV (4 MFMAs, P cols 48..63 zeroed) -> att tile in LDS ->
// outproj (16 MFMAs/wave, Wo frag-major direct global) -> +bias2 -> fp32 out.
#define KROWS 48
#define VROWS 64
#define KVSTR 264
__global__ __launch_bounds__(512) void attn_out_kernel(
    const unsigned short* __restrict__ Y, const float* __restrict__ bias_pack,
    const unsigned short* __restrict__ Wopack, const float* __restrict__ bias2,
    float* __restrict__ out)
{
    __shared__ unsigned short smem[(KROWS + VROWS) * KVSTR];   // 59136 B
    unsigned short* Ks = smem;                      // 48 x 264
    unsigned short* Vs = smem + KROWS * KVSTR;      // 64 x 264
    unsigned short (*Ps)[16][72] = (unsigned short(*)[16][72])smem;   // aliased over K (after scores)
    unsigned short (*As)[KVSTR] = (unsigned short(*)[KVSTR])smem;     // att tile (after PV)

    const int s0 = blockIdx.x * 16;
    const int b = blockIdx.y, dir = blockIdx.z;
    const int kvinp = 1 - dir;
    const int tid = threadIdx.x;

    const float* bkv = bias_pack + kvinp * 768;
    const long kvbase = ((long)kvinp * 8192 + b * 2048) * 768;

    // ---- stage V (64 rows) and K (48 rows), 32 e per task ----
    {
        const int r = tid >> 3, seg = (tid & 7) * 32;
        int p = s0 - 15 + r;
        unsigned short vr[32];
        if (p >= 0 && p < 2048) {
            __builtin_memcpy(vr, Y + kvbase + (long)p * 768 + 512 + seg, 64);
        } else {
            #pragma unroll
            for (int j = 0; j < 32; ++j) vr[j] = f2bf(bkv[512 + seg + j]);
        }
        __builtin_memcpy(&Vs[r * KVSTR + seg], vr, 64);
        if (tid < 384) {   // K rows 0..47
            unsigned short kr[32];
            if (p >= 0 && p < 2048) {
                __builtin_memcpy(kr, Y + kvbase + (long)p * 768 + 256 + seg, 64);
            } else {
                #pragma unroll
                for (int j = 0; j < 32; ++j) kr[j] = f2bf(bkv[256 + seg + j]);
            }
            __builtin_memcpy(&Ks[r * KVSTR + seg], kr, 64);
        }
    }

    // ---- Q fragment (A-layout) direct from global (row-major Y; read-once) ----
    const int lane = tid & 63;
    const int wv = tid >> 6;                    // head index 0..7
    const int fr = lane & 15, q4 = lane >> 4;
    short8 aq = ldg8(Y + ((long)dir * 8192 + b * 2048 + s0 + fr) * 768 + wv * 32 + q4 * 8);

    __syncthreads();   // (1) staging complete

    // ---- scores: S[16 s][48 kv] via 3 MFMAs ----
    floatx4 sacc[3] = {};
    #pragma unroll
    for (int kvt = 0; kvt < 3; ++kvt) {
        short8 bk_ = *(const short8*)&Ks[(kvt * 16 + fr) * KVSTR + wv * 32 + q4 * 8];
        sacc[kvt] = __builtin_amdgcn_mfma_f32_16x16x32_bf16(aq, bk_, sacc[kvt], 0, 0, 0);
    }

    // ---- band mask + softmax (row i = q4*4+reg; kv col jc; 0 <= jc - i <= 30) ----
    float sv[3][4];
    float mx[4] = {-3.0e38f, -3.0e38f, -3.0e38f, -3.0e38f};
    #pragma unroll
    for (int kvt = 0; kvt < 3; ++kvt)
        #pragma unroll
        for (int reg = 0; reg < 4; ++reg) {
            int i = q4 * 4 + reg;
            int jc = kvt * 16 + fr;
            int d = jc - i;
            float x = (d >= 0 && d <= 30) ? sacc[kvt][reg] * 0.17677669529663687f : -3.0e38f;
            sv[kvt][reg] = x;
            mx[reg] = fmaxf(mx[reg], x);
        }
    #pragma unroll
    for (int off = 1; off < 16; off <<= 1)
        #pragma unroll
        for (int reg = 0; reg < 4; ++reg)
            mx[reg] = fmaxf(mx[reg], __shfl_xor(mx[reg], off));
    float ps[4] = {};
    #pragma unroll
    for (int kvt = 0; kvt < 3; ++kvt)
        #pragma unroll
        for (int reg = 0; reg < 4; ++reg) {
            float e = __expf(sv[kvt][reg] - mx[reg]);
            sv[kvt][reg] = e;
            ps[reg] += e;
        }
    #pragma unroll
    for (int off = 1; off < 16; off <<= 1)
        #pragma unroll
        for (int reg = 0; reg < 4; ++reg)
            ps[reg] += __shfl_xor(ps[reg], off);

    __syncthreads();   // (2) all scores read from K; P may overwrite K region

    // ---- P -> LDS bf16 (cols 48..63 zeroed for the K=64 PV) ----
    #pragma unroll
    for (int reg = 0; reg < 4; ++reg) {
        int i = q4 * 4 + reg;
        #pragma unroll
        for (int kvt = 0; kvt < 3; ++kvt)
            Ps[wv][i][kvt * 16 + fr] = f2bf(sv[kvt][reg]);
        Ps[wv][i][48 + fr] = 0;
    }
    // same-wave LDS RAW (P write -> P read) ordered by lgkmcnt; no barrier needed.

    // ---- PV: O[16 s][32 e] via 4 MFMAs (A = own P, B = V^T strided) ----
    floatx4 oacc[2] = {};
    #pragma unroll
    for (int ch = 0; ch < 2; ++ch) {
        short8 ap = *(const short8*)&Ps[wv][fr][ch * 32 + q4 * 8];
        #pragma unroll
        for (int et = 0; et < 2; ++et) {
            short8 bv;
            #pragma unroll
            for (int j = 0; j < 8; ++j)
                bv[j] = (short)Vs[(ch * 32 + q4 * 8 + j) * KVSTR + wv * 32 + et * 16 + fr];
            oacc[et] = __builtin_amdgcn_mfma_f32_16x16x32_bf16(ap, bv, oacc[et], 0, 0, 0);
        }
    }

    float rs[4];
    #pragma unroll
    for (int reg = 0; reg < 4; ++reg) rs[reg] = 1.0f / ps[reg];

    __syncthreads();   // (3) all PV reads done; att tile may overwrite

    #pragma unroll
    for (int et = 0; et < 2; ++et)
        #pragma unroll
        for (int reg = 0; reg < 4; ++reg)
            As[q4 * 4 + reg][wv * 32 + et * 16 + fr] = f2bf(oacc[et][reg] * rs[reg]);

    __syncthreads();   // (4) att tile complete

    // ---- output projection: out[16 x 256] = att @ Wo^T + bias2 (Wo frag-major) ----
    const unsigned short* Wo = Wopack + dir * 65536 + lane * 8;
    const int nw = wv * 32;
    floatx4 oa[2] = {};
    #pragma unroll
    for (int kc = 0; kc < 8; ++kc) {
        short8 ap = *(const short8*)&As[fr][kc * 32 + q4 * 8];
        #pragma unroll
        for (int j = 0; j < 2; ++j) {
            short8 bw = ldg8(Wo + ((wv * 2 + j) * 8 + kc) * 512);   // coalesced frag load
            oa[j] = __builtin_amdgcn_mfma_f32_16x16x32_bf16(ap, bw, oa[j], 0, 0, 0);
        }
    }

    float bj[2];
    #pragma unroll
    for (int j = 0; j < 2; ++j) bj[j] = bias2[dir * 256 + nw + j * 16 + fr];

    float* outp = out + (long)dir * 2097152;
    #pragma unroll
    for (int j = 0; j < 2; ++j)
        #pragma unroll
        for (int reg = 0; reg < 4; ++reg) {
            int i = q4 * 4 + reg;
            outp[((long)b * 2048 + s0 + i) * 256 + nw + j * 16 + fr] = oa[j][reg] + bj[j];
        }
}

// ---------- launch ----------
extern "C" void kernel_launch(void* const* d_in, const int* in_sizes, int n_in,
                              void* d_out, int out_size, void* d_ws, size_t ws_size,
                              hipStream_t stream)
{
    float* out = (float*)d_out;

    char* ws = (char*)d_ws;
    unsigned short* Wpack   = (unsigned short*)(ws + 0);          // 786432 B (frag-major)
    unsigned short* Wopack  = (unsigned short*)(ws + 786432);     // 262144 B (frag-major)
    float*          biasP   = (float*)(ws + 1048576);             // 6144 B
    float*          bias2   = (float*)(ws + 1054720);             // 2048 B
    unsigned short* Y       = (unsigned short*)(ws + 1056768);    // 25165824 B (row-major)
    unsigned short* Abf     = (unsigned short*)(ws + 26222592);   // 8388608 B (frag-major)

    repack_kernel<<<2048, 256, 0, stream>>>(
        (const float*)d_in[2],  (const float*)d_in[3],
        (const float*)d_in[4],  (const float*)d_in[5],
        (const float*)d_in[6],  (const float*)d_in[7],
        (const float*)d_in[8],  (const float*)d_in[9],
        (const float*)d_in[10], (const float*)d_in[11],
        (const float*)d_in[12], (const float*)d_in[13],
        (const float*)d_in[14], (const float*)d_in[15],
        (const float*)d_in[16], (const float*)d_in[17],
        (const float*)d_in[0],  (const float*)d_in[1],
        Wpack, Wopack, biasP, bias2, Abf);

    // fused QKV projection: Abf(frag-major) @ Wpack + bias -> Y (bf16 row-major)
    mfma_gemm_kernel<<<dim3(64, 6, 2), 256, 0, stream>>>(
        Abf, Abf + 2097152, Wpack, Wpack + 196608, biasP, biasP + 768,
        Y, Y + 8192 * 768, 768);

    // fused windowed attention + output projection -> d_out (fp32)
    attn_out_kernel<<<dim3(128, 4, 2), 512, 0, stream>>>(Y, biasP, Wopack, bias2, out);
}

// Round 10
// 138.426 us; speedup vs baseline: 1.1403x; 1.0141x over previous
//
#include <hip/hip_runtime.h>

// ---------- helpers ----------
static __device__ __forceinline__ float bf2f(unsigned short u) {
    return __uint_as_float(((unsigned int)u) << 16);
}
static __device__ __forceinline__ unsigned short f2bf(float f) {
    unsigned int x = __float_as_uint(f);
    unsigned int lsb = (x >> 16) & 1u;
    x += 0x7fffu + lsb;                 // round-to-nearest-even
    return (unsigned short)(x >> 16);
}

typedef __attribute__((ext_vector_type(8))) short short8;    // 8 bf16 = 4 VGPRs (MFMA A/B frag)
typedef __attribute__((ext_vector_type(4))) float floatx4;   // MFMA C/D frag

static __device__ __forceinline__ short8 ldg8(const unsigned short* p) {
    short8 v; __builtin_memcpy(&v, p, 16); return v;
}

// ======================================================================
// FRAGMENT-MAJOR LAYOUT for MFMA operands (16x16x32 bf16):
//   element (row r, k) -> group g=r>>4, fr=r&15, kc=k>>5, q4=(k>>3)&3, j=k&7
//   offset = (g*8 + kc)*512 + (q4*16 + fr)*8 + j      [512 shorts per frag-slot]
// A wave's fragment load = base + lane*8 -> 64 lanes x 16B contiguous = 1KB txn.
// ======================================================================

// ---------- repack: role-partitioned grid, all reads/writes coalesced ----------
// blocks 0..2047: activation fp32 -> bf16 frag-major via LDS transpose (half g-group each)
// blocks 2048..2239: QKV weights (bit-swapped index: n_lo fastest -> coalesced both sides)
// blocks 2240..2303: Wo (same remap)
// blocks 2304..2311: biases fp32
__global__ __launch_bounds__(256) void repack_kernel(
    const float* e2p_Wq, const float* e2p_bq,
    const float* e2p_Wk, const float* e2p_bk,
    const float* e2p_Wv, const float* e2p_bv,
    const float* e2p_Wo, const float* e2p_bo,
    const float* p2e_Wq, const float* p2e_bq,
    const float* p2e_Wk, const float* p2e_bk,
    const float* p2e_Wv, const float* p2e_bv,
    const float* p2e_Wo, const float* p2e_bo,
    const float* eeg, const float* pps,
    unsigned short* Wpack, unsigned short* Wopack, float* bias_pack, float* bias2,
    unsigned short* Abf)
{
    __shared__ unsigned short tr[2048];   // 4 KB transpose buffer (activation blocks)
    const int bid = blockIdx.x, tid = threadIdx.x;

    if (bid < 2048) {
        // --- activations: block = (g = bid>>1, kc_half = (bid&1)*4) ---
        const int g = bid >> 1, kc_half = (bid & 1) * 4;
        const int inp = g >> 9;
        const int m = (g & 511) * 16 + (tid >> 4);       // per-input row
        const int k8 = kc_half * 4 + (tid & 15);         // 8-elem k-slot
        const float* src = inp ? pps : eeg;
        float v[8];
        __builtin_memcpy(v, src + (long)m * 256 + k8 * 8, 32);   // coalesced 32B
        unsigned short o[8];
        #pragma unroll
        for (int j = 0; j < 8; ++j) o[j] = f2bf(v[j]);
        const int k8l = tid & 15;
        __builtin_memcpy(&tr[(k8l >> 2) * 512 + ((k8l & 3) * 16 + (tid >> 4)) * 8], o, 16);
        __syncthreads();
        unsigned short t[8];
        __builtin_memcpy(t, &tr[tid * 8], 16);
        __builtin_memcpy(Abf + inp * 2097152 + ((g & 511) * 8 + kc_half) * 512 + tid * 8, t, 16);  // linear 4KB
        return;
    }
    if (bid < 2240) {
        // --- QKV weights: 49152 slots; n_lo fastest for coalescing ---
        int idx = (bid - 2048) * 256 + tid;
        int inp = idx / 24576, r = idx % 24576;
        int n = (r & 15) | ((r >> 9) << 4);              // 0..767
        int k8 = (r >> 4) & 31;
        int kc = k8 >> 2, q4 = k8 & 3, kb = k8 * 8;
        int proj = n / 256, h = (n % 256) / 32, e = n % 32;
        const float* W;
        if (inp == 0) W = (proj == 0) ? e2p_Wq : (proj == 1) ? p2e_Wk : p2e_Wv;
        else          W = (proj == 0) ? p2e_Wq : (proj == 1) ? e2p_Wk : e2p_Wv;
        unsigned short o[8];
        #pragma unroll
        for (int j = 0; j < 8; ++j) o[j] = f2bf(W[h * 8192 + (kb + j) * 32 + e]);
        __builtin_memcpy(Wpack + inp * 196608 + ((n >> 4) * 8 + kc) * 512 + (q4 * 16 + (n & 15)) * 8, o, 16);
        return;
    }
    if (bid < 2304) {
        // --- Wo: 16384 slots (row n of Wo^T = col n of Wo) ---
        int i2 = (bid - 2240) * 256 + tid;
        int dir = i2 / 8192, r = i2 % 8192;
        int n = (r & 15) | ((r >> 9) << 4);              // 0..255
        int k8 = (r >> 4) & 31;
        int kc = k8 >> 2, q4 = k8 & 3, kb = k8 * 8;
        const float* Wo = dir ? p2e_Wo : e2p_Wo;
        unsigned short o[8];
        #pragma unroll
        for (int j = 0; j < 8; ++j) o[j] = f2bf(Wo[(kb + j) * 256 + n]);
        __builtin_memcpy(Wopack + dir * 65536 + ((n >> 4) * 8 + kc) * 512 + (q4 * 16 + (n & 15)) * 8, o, 16);
        return;
    }
    // --- biases ---
    {
        int idx = (bid - 2304) * 256 + tid;   // 0..2047
        if (idx < 1536) {
            int inp = idx / 768, n = idx % 768;
            int proj = n / 256, he = n % 256;
            const float* bsrc;
            if (inp == 0) bsrc = (proj == 0) ? e2p_bq : (proj == 1) ? p2e_bk : p2e_bv;
            else          bsrc = (proj == 0) ? p2e_bq : (proj == 1) ? e2p_bk : e2p_bv;
            bias_pack[idx] = bsrc[he];
        } else {
            int j = idx - 1536;
            int dir = j / 256, n = j % 256;
            bias2[j] = (dir == 0 ? e2p_bo : p2e_bo)[n];
        }
    }
}

// ---------- MFMA GEMM, barrier-free K-loop, frag-major operands (unchanged from R9) ----------
__global__ __launch_bounds__(256) void mfma_gemm_kernel(
    const unsigned short* __restrict__ A0, const unsigned short* __restrict__ A1,
    const unsigned short* __restrict__ B0f, const unsigned short* __restrict__ B1f,
    const float* __restrict__ bias0, const float* __restrict__ bias1,
    unsigned short* __restrict__ C0, unsigned short* __restrict__ C1,
    int N)
{
    __shared__ __align__(16) unsigned short Cs[128][136];   // epilogue only

    const int z = blockIdx.z;
    const unsigned short* A = z ? A1 : A0;
    const unsigned short* Bf = z ? B1f : B0f;
    const float* bias = z ? bias1 : bias0;
    unsigned short* C = z ? C1 : C0;

    const int tid = threadIdx.x;
    const long m0 = (long)blockIdx.x * 128;
    const int n0 = blockIdx.y * 128;

    const int lane = tid & 63;
    const int wv = tid >> 6;
    const int wm = (wv >> 1) * 64, wn = (wv & 1) * 64;
    const int fr = lane & 15, q4 = lane >> 4;

    const unsigned short* Aw = A + ((blockIdx.x * 8 + (wm >> 4)) * 8) * 512 + lane * 8;
    const unsigned short* Bw = Bf + ((blockIdx.y * 8 + (wn >> 4)) * 8) * 512 + lane * 8;

    floatx4 acc[4][4] = {};
    short8 af[2][4], bf_[2][4];

    #pragma unroll
    for (int i = 0; i < 4; ++i) af[0][i] = ldg8(Aw + i * 4096);
    #pragma unroll
    for (int j = 0; j < 4; ++j) bf_[0][j] = ldg8(Bw + j * 4096);

    #pragma unroll
    for (int kc = 0; kc < 8; ++kc) {
        const int cur = kc & 1, nxt = cur ^ 1;
        if (kc < 7) {
            #pragma unroll
            for (int i = 0; i < 4; ++i) af[nxt][i] = ldg8(Aw + (i * 8 + kc + 1) * 512);
            #pragma unroll
            for (int j = 0; j < 4; ++j) bf_[nxt][j] = ldg8(Bw + (j * 8 + kc + 1) * 512);
        }
        #pragma unroll
        for (int i = 0; i < 4; ++i)
            #pragma unroll
            for (int j = 0; j < 4; ++j)
                acc[i][j] = __builtin_amdgcn_mfma_f32_16x16x32_bf16(af[cur][i], bf_[cur][j], acc[i][j], 0, 0, 0);
    }

    float bj[4];
    #pragma unroll
    for (int j = 0; j < 4; ++j) bj[j] = bias[n0 + wn + j * 16 + fr];

    const int cr0 = wm + (q4 << 2);
    #pragma unroll
    for (int i = 0; i < 4; ++i)
        #pragma unroll
        for (int j = 0; j < 4; ++j)
            #pragma unroll
            for (int r = 0; r < 4; ++r)
                Cs[cr0 + i * 16 + r][wn + j * 16 + fr] = f2bf(acc[i][j][r] + bj[j]);
    __syncthreads();

    const int rr = tid >> 4, cc = (tid & 15) * 8;
    #pragma unroll
    for (int p = 0; p < 8; ++p) {
        int r = p * 16 + rr;
        unsigned short tmp[8];
        __builtin_memcpy(tmp, &Cs[r][cc], 16);
        __builtin_memcpy(C + (m0 + r) * N + n0 + cc, tmp, 16);
    }
}

// ---------- fused MFMA attention + output projection ----------
// Block = (s-tile of 16, b, dir), 512 thr = 8 waves, one head per wave.
// K rows 0..47 / V rows 0..63 staged in LDS (OOB rows = bias vectors, NOT masked —
// reference pads kv BEFORE projection). Scores (3 MFMAs) -> band mask -> softmax ->
// P (aliased over K) -> PV (4 MFMAs) -> att tile -> outproj (Wo frag-major) ->
// fp32 tile through LDS -> coalesced 32B stores.
#define KROWS 48
#define VROWS 64
#define KVSTR 264
__global__ __launch_bounds__(512) void attn_out_kernel(
    const unsigned short* __restrict__ Y, const float* __restrict__ bias_pack,
    const unsigned short* __restrict__ Wopack, const float* __restrict__ bias2,
    float* __restrict__ out)
{
    __shared__ __align__(16) unsigned short smem[(KROWS + VROWS) * KVSTR];   // 59136 B
    unsigned short* Ks = smem;                      // 48 x 264
    unsigned short* Vs = smem + KROWS * KVSTR;      // 64 x 264
    unsigned short (*Ps)[16][72] = (unsigned short(*)[16][72])smem;   // aliased over K (after scores)
    unsigned short (*As)[KVSTR] = (unsigned short(*)[KVSTR])smem;     // att tile (after PV)
    float (*Os)[264] = (float(*)[264])smem;                           // fp32 out tile (after outproj)

    const int s0 = blockIdx.x * 16;
    const int b = blockIdx.y, dir = blockIdx.z;
    const int kvinp = 1 - dir;
    const int tid = threadIdx.x;

    const float* bkv = bias_pack + kvinp * 768;
    const long kvbase = ((long)kvinp * 8192 + b * 2048) * 768;

    // ---- stage V (64 rows) and K (48 rows), 32 e per task ----
    {
        const int r = tid >> 3, seg = (tid & 7) * 32;
        int p = s0 - 15 + r;
        unsigned short vr[32];
        if (p >= 0 && p < 2048) {
            __builtin_memcpy(vr, Y + kvbase + (long)p * 768 + 512 + seg, 64);
        } else {
            #pragma unroll
            for (int j = 0; j < 32; ++j) vr[j] = f2bf(bkv[512 + seg + j]);
        }
        __builtin_memcpy(&Vs[r * KVSTR + seg], vr, 64);
        if (tid < 384) {   // K rows 0..47
            unsigned short kr[32];
            if (p >= 0 && p < 2048) {
                __builtin_memcpy(kr, Y + kvbase + (long)p * 768 + 256 + seg, 64);
            } else {
                #pragma unroll
                for (int j = 0; j < 32; ++j) kr[j] = f2bf(bkv[256 + seg + j]);
            }
            __builtin_memcpy(&Ks[r * KVSTR + seg], kr, 64);
        }
    }

    // ---- Q fragment (A-layout) direct from global ----
    const int lane = tid & 63;
    const int wv = tid >> 6;                    // head index 0..7
    const int fr = lane & 15, q4 = lane >> 4;
    short8 aq = ldg8(Y + ((long)dir * 8192 + b * 2048 + s0 + fr) * 768 + wv * 32 + q4 * 8);

    __syncthreads();   // (1) staging complete

    // ---- scores: S[16 s][48 kv] via 3 MFMAs ----
    floatx4 sacc[3] = {};
    #pragma unroll
    for (int kvt = 0; kvt < 3; ++kvt) {
        short8 bk_ = *(const short8*)&Ks[(kvt * 16 + fr) * KVSTR + wv * 32 + q4 * 8];
        sacc[kvt] = __builtin_amdgcn_mfma_f32_16x16x32_bf16(aq, bk_, sacc[kvt], 0, 0, 0);
    }

    // ---- band mask + softmax (row i = q4*4+reg; kv col jc; 0 <= jc - i <= 30) ----
    float sv[3][4];
    float mx[4] = {-3.0e38f, -3.0e38f, -3.0e38f, -3.0e38f};
    #pragma unroll
    for (int kvt = 0; kvt < 3; ++kvt)
        #pragma unroll
        for (int reg = 0; reg < 4; ++reg) {
            int i = q4 * 4 + reg;
            int jc = kvt * 16 + fr;
            int d = jc - i;
            float x = (d >= 0 && d <= 30) ? sacc[kvt][reg] * 0.17677669529663687f : -3.0e38f;
            sv[kvt][reg] = x;
            mx[reg] = fmaxf(mx[reg], x);
        }
    #pragma unroll
    for (int off = 1; off < 16; off <<= 1)
        #pragma unroll
        for (int reg = 0; reg < 4; ++reg)
            mx[reg] = fmaxf(mx[reg], __shfl_xor(mx[reg], off));
    float ps[4] = {};
    #pragma unroll
    for (int kvt = 0; kvt < 3; ++kvt)
        #pragma unroll
        for (int reg = 0; reg < 4; ++reg) {
            float e = __expf(sv[kvt][reg] - mx[reg]);
            sv[kvt][reg] = e;
            ps[reg] += e;
        }
    #pragma unroll
    for (int off = 1; off < 16; off <<= 1)
        #pragma unroll
        for (int reg = 0; reg < 4; ++reg)
            ps[reg] += __shfl_xor(ps[reg], off);

    __syncthreads();   // (2) all scores read from K; P may overwrite K region

    // ---- P -> LDS bf16 (cols 48..63 zeroed for the K=64 PV) ----
    #pragma unroll
    for (int reg = 0; reg < 4; ++reg) {
        int i = q4 * 4 + reg;
        #pragma unroll
        for (int kvt = 0; kvt < 3; ++kvt)
            Ps[wv][i][kvt * 16 + fr] = f2bf(sv[kvt][reg]);
        Ps[wv][i][48 + fr] = 0;
    }
    // same-wave LDS RAW (P write -> P read) ordered by lgkmcnt; no barrier needed.

    // ---- PV: O[16 s][32 e] via 4 MFMAs (A = own P, B = V^T strided) ----
    floatx4 oacc[2] = {};
    #pragma unroll
    for (int ch = 0; ch < 2; ++ch) {
        short8 ap = *(const short8*)&Ps[wv][fr][ch * 32 + q4 * 8];
        #pragma unroll
        for (int et = 0; et < 2; ++et) {
            short8 bv;
            #pragma unroll
            for (int j = 0; j < 8; ++j)
                bv[j] = (short)Vs[(ch * 32 + q4 * 8 + j) * KVSTR + wv * 32 + et * 16 + fr];
            oacc[et] = __builtin_amdgcn_mfma_f32_16x16x32_bf16(ap, bv, oacc[et], 0, 0, 0);
        }
    }

    float rs[4];
    #pragma unroll
    for (int reg = 0; reg < 4; ++reg) rs[reg] = 1.0f / ps[reg];

    __syncthreads();   // (3) all PV reads done; att tile may overwrite

    #pragma unroll
    for (int et = 0; et < 2; ++et)
        #pragma unroll
        for (int reg = 0; reg < 4; ++reg)
            As[q4 * 4 + reg][wv * 32 + et * 16 + fr] = f2bf(oacc[et][reg] * rs[reg]);

    __syncthreads();   // (4) att tile complete

    // ---- output projection: out[16 x 256] = att @ Wo^T + bias2 (Wo frag-major) ----
    const unsigned short* Wo = Wopack + dir * 65536 + lane * 8;
    const int nw = wv * 32;
    floatx4 oa[2] = {};
    #pragma unroll
    for (int kc = 0; kc < 8; ++kc) {
        short8 ap = *(const short8*)&As[fr][kc * 32 + q4 * 8];
        #pragma unroll
        for (int j = 0; j < 2; ++j) {
            short8 bw = ldg8(Wo + ((wv * 2 + j) * 8 + kc) * 512);   // coalesced frag load
            oa[j] = __builtin_amdgcn_mfma_f32_16x16x32_bf16(ap, bw, oa[j], 0, 0, 0);
        }
    }

    float bj[2];
    #pragma unroll
    for (int j = 0; j < 2; ++j) bj[j] = bias2[dir * 256 + nw + j * 16 + fr];

    __syncthreads();   // (5) all As reads done; Os may overwrite

    #pragma unroll
    for (int j = 0; j < 2; ++j)
        #pragma unroll
        for (int reg = 0; reg < 4; ++reg)
            Os[q4 * 4 + reg][nw + j * 16 + fr] = oa[j][reg] + bj[j];

    __syncthreads();   // (6) fp32 tile complete

    const int row = tid >> 5, col = (tid & 31) * 8;
    float t8[8];
    __builtin_memcpy(t8, &Os[row][col], 32);
    __builtin_memcpy(out + (long)dir * 2097152 + ((long)b * 2048 + s0 + row) * 256 + col, t8, 32);
}

// ---------- launch ----------
extern "C" void kernel_launch(void* const* d_in, const int* in_sizes, int n_in,
                              void* d_out, int out_size, void* d_ws, size_t ws_size,
                              hipStream_t stream)
{
    float* out = (float*)d_out;

    char* ws = (char*)d_ws;
    unsigned short* Wpack   = (unsigned short*)(ws + 0);          // 786432 B (frag-major)
    unsigned short* Wopack  = (unsigned short*)(ws + 786432);     // 262144 B (frag-major)
    float*          biasP   = (float*)(ws + 1048576);             // 6144 B
    float*          bias2   = (float*)(ws + 1054720);             // 2048 B
    unsigned short* Y       = (unsigned short*)(ws + 1056768);    // 25165824 B (row-major)
    unsigned short* Abf     = (unsigned short*)(ws + 26222592);   // 8388608 B (frag-major)

    repack_kernel<<<2312, 256, 0, stream>>>(
        (const float*)d_in[2],  (const float*)d_in[3],
        (const float*)d_in[4],  (const float*)d_in[5],
        (const float*)d_in[6],  (const float*)d_in[7],
        (const float*)d_in[8],  (const float*)d_in[9],
        (const float*)d_in[10], (const float*)d_in[11],
        (const float*)d_in[12], (const float*)d_in[13],
        (const float*)d_in[14], (const float*)d_in[15],
        (const float*)d_in[16], (const float*)d_in[17],
        (const float*)d_in[0],  (const float*)d_in[1],
        Wpack, Wopack, biasP, bias2, Abf);

    // fused QKV projection: Abf(frag-major) @ Wpack + bias -> Y (bf16 row-major)
    mfma_gemm_kernel<<<dim3(64, 6, 2), 256, 0, stream>>>(
        Abf, Abf + 2097152, Wpack, Wpack + 196608, biasP, biasP + 768,
        Y, Y + 8192 * 768, 768);

    // fused windowed attention + output projection -> d_out (fp32)
    attn_out_kernel<<<dim3(128, 4, 2), 512, 0, stream>>>(Y, biasP, Wopack, bias2, out);
}